// Round 6
// baseline (1182.109 us; speedup 1.0000x reference)
//
#include <hip/hip_runtime.h>
#include <hip/hip_bf16.h>

// EGNN encoder, N=50000, E=250000, D=128, L=4. bf16 inputs/output (verified R2).
// R3: CSR-by-tgt aggregation (no atomics), EW2@NW1b folding.
// R4: 3-stage parallel CSR scan.  R5: agg chunked x4 + fast rcp.
// R7: weight-stationary streaming matmuls.  R10: bf16-only residual stream.
// R11: merged setup kernel. 524us.
// R12 FAILED: cooperative front-end fusion (+350us, occupancy-starved).
// R13 FAILED: 512-thread mm blocks; exposed scattered-2B store amplification.
// R14: fragment-swizzled internal tensors (mm fixed, agg regressed). 563us.
// R15: split layouts per consumer (Ab/Bb/Hb row-major for agg, xb/hb swizzled
//     for MFMA; mm_ab stages C-tiles through per-wave LDS). 518us. agg now
//     VALU/latency-bound; mm kernels ~22us each vs ~6us roofline -> 2 blocks/CU
//     (64KB weight LDS) = 2 waves/SIMD is the limiter.
// R16: weights from L1/L2 instead of LDS. B-fragments read directly from
//     global (coalesced 1KB/inst, 96KB working set is L2-resident); weight-LDS
//     and its barrier deleted -> occupancy VGPR-limited (12-16+ waves/CU).
//     mm_ab keeps 16KB per-wave C-stage; mm_res<1> gains same stage so d_out
//     is full-line. MMGRID 512->782 (1 tile/wave).
// R17: identical resubmit of R16 (round 5 failed with "container failed twice"
//     infra error before any measurement; source audit found no container-killer).

#define NNODES 50000
#define NEDGES 250000
#define NTILES 3125   // 50000/16 exactly, no tail
#define MMGRID 782    // 782 blocks x 4 waves = 3128 waves >= 3125 tiles
#define RGRID  1024

typedef unsigned short u16;
typedef __attribute__((ext_vector_type(8))) short bf16x8;
typedef __attribute__((ext_vector_type(4))) float floatx4;

__device__ __forceinline__ float b2f(u16 h){ unsigned u=((unsigned)h)<<16; float f; __builtin_memcpy(&f,&u,4); return f; }
__device__ __forceinline__ u16 f2b(float f){ unsigned u; __builtin_memcpy(&u,&f,4); u = u + 0x7FFFu + ((u>>16)&1u); return (u16)(u>>16); }
__device__ __forceinline__ float siluf(float x){ return x*__builtin_amdgcn_rcpf(1.f+__expf(-x)); }
__device__ __forceinline__ float ldf(const void* p, long i, int isbf){
  return isbf ? b2f(((const u16*)p)[i]) : ((const float*)p)[i];
}
// swizzled element offset for MFMA-internal N x 128 tensors (xb, hb):
// [tile][ (col>>4)*4 + (row&3) ][ ((row&15)>>2)*16 + (col&15) ]
__device__ __forceinline__ long swz(long row, int col){
  return (row>>4)*2048 + (long)(((col>>4)*4 + (int)(row&3))*64 + (((int)(row&15))>>2)*16 + (col&15));
}

__global__ void detect_kernel(const void* lng, int* flag){
  if (threadIdx.x==0 && blockIdx.x==0) *flag = (((const u16*)lng)[0] != 0) ? 1 : 0;
}

// ---------- merged setup: phases partitioned by blockIdx ----------
#define SU_W12   192
#define SU_EBW   704
#define SU_W2P   708
#define SU_PPARM 712
#define SU_PROJ  713
#define SU_CVTP  25713
#define SU_END   26104
__global__ __launch_bounds__(256) void setup_kernel(
    const void* __restrict__ ew1, const void* __restrict__ ew2,
    const void* __restrict__ nw1, const void* __restrict__ nw2,
    u16* __restrict__ packed,
    const void* __restrict__ eb2, const void* __restrict__ pw1,
    const void* __restrict__ pb1, const void* __restrict__ pw2v, const void* __restrict__ pb2,
    float* __restrict__ w2p, float* __restrict__ c2p, float* __restrict__ pparm,
    float* __restrict__ ebW,
    const void* __restrict__ nf, const void* __restrict__ npw, const void* __restrict__ npb,
    u16* __restrict__ xb,
    const void* __restrict__ pos, float* __restrict__ pf,
    const int* __restrict__ flagp)
{
  const int isbf = *flagp;
  const int b = blockIdx.x, tid = threadIdx.x;
  __shared__ float red[128];
  if (b < SU_W12){
    // ---- pack 24 matrices ----
    int t = b*256 + tid;
    int m = t >> 11; int r = t & 2047;
    int lane = r & 63; int ntk = r >> 6;
    int kk = ntk >> 3, nt = ntk & 7;
    int l = m/6, w = m%6;
    const void* src; long off;
    switch(w){
      case 0: src=ew1; off=(long)l*257*128;            break; // W1a
      case 1: src=ew1; off=(long)l*257*128 + 128*128;  break; // W1b
      case 2: src=ew2; off=(long)l*128*128;            break; // EW2 (layout slot)
      case 3: src=nw1; off=(long)l*256*128;            break; // NW1a
      case 4: src=nw1; off=(long)l*256*128 + 128*128;  break; // NW1b (unused)
      default:src=nw2; off=(long)l*128*128;            break; // NW2
    }
    int c  = nt*16 + (lane & 15);
    int k0 = kk*32 + (lane >> 4)*8;
    u16 vals[8];
#pragma unroll
    for (int j=0;j<8;j++){
      long idx = off + (long)(k0+j)*128 + c;
      vals[j] = isbf ? ((const u16*)src)[idx] : f2b(((const float*)src)[idx]);
    }
    bf16x8 v; __builtin_memcpy(&v, vals, 16);
    *(bf16x8*)(packed + (long)t*8) = v;
  } else if (b < SU_EBW){
    // ---- W12[l][k][j] -> packed chunk 24+l, fragment position ----
    int bb = b - SU_W12;
    int l = bb >> 7, k = bb & 127;
    if (tid < 128){
      int j = tid;
      long e2 = (long)l*16384 + (long)k*128;
      long nb = (long)l*256*128 + 128*128;
      float acc = 0.f;
      for (int d=0; d<128; d++)
        acc += ldf(ew2, e2 + d, isbf) * ldf(nw1, nb + (long)d*128 + j, isbf);
      int kk = k>>5, lane = ((k>>3)&3)*16 + (j&15), nt = j>>4, jj = k&7;
      packed[(long)(24+l)*16384 + (long)((kk*8+nt)*64 + lane)*8 + jj] = f2b(acc);
    }
  } else if (b < SU_W2P){
    int l = b - SU_EBW;
    if (tid < 128){
      int j = tid;
      long nb = (long)l*256*128 + 128*128;
      float acc = 0.f;
      for (int d=0; d<128; d++)
        acc += ldf(eb2, (long)l*128 + d, isbf) * ldf(nw1, nb + (long)d*128 + j, isbf);
      ebW[l*128+j] = acc;
    }
  } else if (b < SU_PPARM){
    int l = b - SU_W2P;
    int i = tid;
    long Woff = (long)l*128*128, poff = (long)l*129;
    if (i < 128){
      float acc = 0.f;
      for (int j=0;j<128;j++) acc += ldf(ew2, Woff + (long)i*128 + j, isbf) * ldf(pw1, poff + j, isbf);
      w2p[l*128+i] = acc;
      red[i] = ldf(eb2, (long)l*128 + i, isbf) * ldf(pw1, poff + i, isbf);
    }
    __syncthreads();
    for (int st=64; st>0; st>>=1){ if (i<st) red[i]+=red[i+st]; __syncthreads(); }
    if (i==0) c2p[l] = red[0];
  } else if (b == SU_PPARM){
    int l = tid;
    if (l < 4){
      pparm[l*4+0] = ldf(pw1, (long)l*129 + 128, isbf);
      pparm[l*4+1] = ldf(pb1, l, isbf);
      pparm[l*4+2] = ldf(pw2v, l, isbf);
      pparm[l*4+3] = ldf(pb2, l, isbf);
    }
  } else if (b < SU_CVTP){
    int n = (b - SU_PROJ)*2 + (tid>>7), d = tid & 127;
    if (n < NNODES){
      float acc = ldf(npb, d, isbf);
#pragma unroll
      for (int f=0; f<12; f++) acc += ldf(nf, (long)n*12+f, isbf) * ldf(npw, f*128+d, isbf);
      xb[swz(n, d)] = f2b(acc);   // swizzled residual layout
    }
  } else {
    int i = (b - SU_CVTP)*256 + tid;
    if (i < 2*NNODES) pf[i] = ldf(pos, i, isbf);
  }
}

// ---------- CSR build: histogram, 3-stage scan, scatter ----------
__global__ __launch_bounds__(256) void hist_kernel(const int* __restrict__ tgt, int* __restrict__ cnt, int E){
  int i = blockIdx.x*256 + threadIdx.x;
  if (i < E) atomicAdd(&cnt[tgt[i]], 1);
}

__global__ __launch_bounds__(256) void bsum_kernel(const int* __restrict__ cnt, int* __restrict__ bsum, int N){
  int i = blockIdx.x*256 + threadIdx.x;
  int v = (i < N) ? cnt[i] : 0;
#pragma unroll
  for (int off=32; off; off>>=1) v += __shfl_down(v, off);
  __shared__ int ws[4];
  if ((threadIdx.x & 63) == 0) ws[threadIdx.x>>6] = v;
  __syncthreads();
  if (threadIdx.x == 0) bsum[blockIdx.x] = ws[0]+ws[1]+ws[2]+ws[3];
}

__global__ __launch_bounds__(256) void bscan_kernel(int* __restrict__ bsum, int nb){
  __shared__ int lds[256];
  int i = threadIdx.x;
  int v = (i < nb) ? bsum[i] : 0;
  lds[i] = v; __syncthreads();
#pragma unroll
  for (int off=1; off<256; off<<=1){
    int t = (i>=off)? lds[i-off] : 0; __syncthreads();
    lds[i] += t; __syncthreads();
  }
  if (i < nb) bsum[i] = lds[i] - v;  // exclusive prefix
}

__global__ __launch_bounds__(256) void csr_kernel(
    const int* __restrict__ cnt, const int* __restrict__ bsum,
    int* __restrict__ rowptr, int* __restrict__ cursor, float* __restrict__ degf, int N)
{
  __shared__ int lds[256];
  int i = blockIdx.x*256 + threadIdx.x;
  int c = (i < N) ? cnt[i] : 0;
  lds[threadIdx.x] = c; __syncthreads();
#pragma unroll
  for (int off=1; off<256; off<<=1){
    int t = (threadIdx.x>=off)? lds[threadIdx.x-off] : 0; __syncthreads();
    lds[threadIdx.x] += t; __syncthreads();
  }
  int run = bsum[blockIdx.x] + lds[threadIdx.x] - c;  // exclusive
  if (i < N){
    rowptr[i] = run; cursor[i] = run; degf[i] = (float)c;
    if (i == N-1) rowptr[N] = run + c;
  }
}

__global__ __launch_bounds__(256) void scatter_kernel(
    const int* __restrict__ src, const int* __restrict__ tgt,
    int* __restrict__ cursor, int* __restrict__ permsrc, int E)
{
  int e = blockIdx.x*256 + threadIdx.x;
  if (e >= E) return;
  int t = tgt[e];
  int p = atomicAdd(&cursor[t], 1);
  permsrc[p] = src[e];
}

// ---------- streaming A/B matmul: Ab = bf16(x@Wa+eb1), Bb = bf16(x@Wb) ----------
// X swizzled; weights read directly from global (L1/L2-resident, coalesced 1KB/inst).
// Ab/Bb row-major via per-wave 4KB LDS stage (16KB static total, no barrier).
__global__ __launch_bounds__(256, 3) void mm_ab_kernel(
    const u16* __restrict__ X, const u16* __restrict__ Wa, const u16* __restrict__ Wb,
    const void* __restrict__ bias, long bias_off,
    u16* __restrict__ Ab, u16* __restrict__ Bb, const int* __restrict__ flagp)
{
  __shared__ u16 sw_[8192];   // 4 waves x 4KB
  const int tid = threadIdx.x, wave = tid>>6, lane = tid&63;
  const int isbf = *flagp;
  const int lr = lane&15, lg = lane>>4;
  float biasv[8];
#pragma unroll
  for (int nt=0;nt<8;nt++) biasv[nt] = ldf(bias, bias_off + nt*16 + lr, isbf);
  int aoff[4];
#pragma unroll
  for (int kk=0;kk<4;kk++) aoff[kk] = ((2*kk + (lg>>1))*4 + (lr&3))*64 + (lr>>2)*16 + (lg&1)*8;
  u16* sw = sw_ + (wave<<11);
  for (int tile = blockIdx.x*4 + wave; tile < NTILES; tile += MMGRID*4){
    const u16* xt = X + (long)tile*2048;
    bf16x8 a[4];
#pragma unroll
    for (int kk=0;kk<4;kk++) a[kk] = *(const bf16x8*)(xt + aoff[kk]);
    floatx4 accA[8], accB[8];
#pragma unroll
    for (int i=0;i<8;i++){ accA[i]=(floatx4){0,0,0,0}; accB[i]=(floatx4){0,0,0,0}; }
#pragma unroll
    for (int kk=0;kk<4;kk++){
#pragma unroll
      for (int nt=0;nt<8;nt++){
        bf16x8 ba = *(const bf16x8*)(Wa + ((kk*8+nt)*64 + lane)*8);
        accA[nt] = __builtin_amdgcn_mfma_f32_16x16x32_bf16(a[kk], ba, accA[nt], 0, 0, 0);
        bf16x8 bb = *(const bf16x8*)(Wb + ((kk*8+nt)*64 + lane)*8);
        accB[nt] = __builtin_amdgcn_mfma_f32_16x16x32_bf16(a[kk], bb, accB[nt], 0, 0, 0);
      }
    }
    // ---- stage A through LDS -> row-major coalesced stores ----
    u16* at = Ab + (long)tile*2048;
#pragma unroll
    for (int r=0;r<4;r++){
#pragma unroll
      for (int nt=0;nt<8;nt++) sw[(lg*4+r)*128 + nt*16 + lr] = f2b(accA[nt][r] + biasv[nt]);
    }
#pragma unroll
    for (int j=0;j<4;j++){
      bf16x8 v = *(const bf16x8*)(sw + j*512 + lane*8);
      *(bf16x8*)(at + j*512 + lane*8) = v;
    }
    // ---- stage B (same region; per-wave DS ops are in-order) ----
    u16* bt = Bb + (long)tile*2048;
#pragma unroll
    for (int r=0;r<4;r++){
#pragma unroll
      for (int nt=0;nt<8;nt++) sw[(lg*4+r)*128 + nt*16 + lr] = f2b(accB[nt][r]);
    }
#pragma unroll
    for (int j=0;j<4;j++){
      bf16x8 v = *(const bf16x8*)(sw + j*512 + lane*8);
      *(bf16x8*)(bt + j*512 + lane*8) = v;
    }
  }
}

// ---------- streaming hidden matmul: hb = bf16(silu(xb@NW1a + Hb@W12 + deg*ebW + nb1)) ----------
// X (xb) swizzled; H (Hb) row-major; hb out swizzled. Weights from L1/L2. No LDS.
__global__ __launch_bounds__(256, 4) void mm_hidden_kernel(
    const u16* __restrict__ X, const u16* __restrict__ H,
    const u16* __restrict__ W1, const u16* __restrict__ W2,
    const void* __restrict__ nb1, long nb1_off,
    const float* __restrict__ degf, const float* __restrict__ ebW,
    u16* __restrict__ hb, const int* __restrict__ flagp)
{
  const int tid = threadIdx.x, wave = tid>>6, lane = tid&63;
  const int isbf = *flagp;
  const int lr = lane&15, lg = lane>>4;
  float nb1v[8], ebv[8];
#pragma unroll
  for (int nt=0;nt<8;nt++){ int col=nt*16+lr; nb1v[nt]=ldf(nb1, nb1_off+col, isbf); ebv[nt]=ebW[col]; }
  int aoff[4];
#pragma unroll
  for (int kk=0;kk<4;kk++) aoff[kk] = ((2*kk + (lg>>1))*4 + (lr&3))*64 + (lr>>2)*16 + (lg&1)*8;
  for (int tile = blockIdx.x*4 + wave; tile < NTILES; tile += MMGRID*4){
    const u16* xt = X + (long)tile*2048;
    const u16* hr = H + ((long)tile*16 + lr)*128;   // row-major H
    bf16x8 ax[4], ah[4];
#pragma unroll
    for (int kk=0;kk<4;kk++){
      ax[kk] = *(const bf16x8*)(xt + aoff[kk]);
      ah[kk] = *(const bf16x8*)(hr + kk*32 + lg*8);
    }
    floatx4 acc[8];
#pragma unroll
    for (int i=0;i<8;i++) acc[i]=(floatx4){0,0,0,0};
#pragma unroll
    for (int kk=0;kk<4;kk++){
#pragma unroll
      for (int nt=0;nt<8;nt++){
        bf16x8 b1 = *(const bf16x8*)(W1 + ((kk*8+nt)*64 + lane)*8);
        acc[nt] = __builtin_amdgcn_mfma_f32_16x16x32_bf16(ax[kk], b1, acc[nt], 0, 0, 0);
        bf16x8 b2 = *(const bf16x8*)(W2 + ((kk*8+nt)*64 + lane)*8);
        acc[nt] = __builtin_amdgcn_mfma_f32_16x16x32_bf16(ah[kk], b2, acc[nt], 0, 0, 0);
      }
    }
    float dv[4];
#pragma unroll
    for (int r=0;r<4;r++) dv[r] = degf[(long)tile*16 + lg*4 + r];
    u16* ot = hb + (long)tile*2048;   // swizzled direct store (full lines)
#pragma unroll
    for (int r=0;r<4;r++){
#pragma unroll
      for (int nt=0;nt<8;nt++){
        ot[(nt*4+r)*64 + lane] = f2b(siluf(acc[nt][r] + nb1v[nt] + dv[r]*ebv[nt]));
      }
    }
  }
}

// ---------- streaming residual matmul (bf16 residual stream), grid RGRID ----------
// H (hb) swizzled; xb swizzled RMW; weights from L1/L2.
// LN=1: layernorm -> d_out row-major via per-wave LDS stage (bf16 path).
template<int LN>
__global__ __launch_bounds__(256, 4) void mm_res_kernel(
    const u16* __restrict__ H, const u16* __restrict__ W,
    const void* __restrict__ nb2, long nb2_off,
    u16* __restrict__ xb,
    const void* __restrict__ lng, const void* __restrict__ lnb, void* __restrict__ outp,
    const int* __restrict__ flagp)
{
  __shared__ u16 sw_[8192];
  const int tid = threadIdx.x, wave = tid>>6, lane = tid&63;
  const int isbf = *flagp;
  const int lr = lane&15, lg = lane>>4;
  float nb2v[8];
#pragma unroll
  for (int nt=0;nt<8;nt++) nb2v[nt] = ldf(nb2, nb2_off + nt*16 + lr, isbf);
  float gv[8], bvv[8];
  if (LN){
#pragma unroll
    for (int nt=0;nt<8;nt++){ int col=nt*16+lr; gv[nt]=ldf(lng,col,isbf); bvv[nt]=ldf(lnb,col,isbf); }
  }
  int aoff[4];
#pragma unroll
  for (int kk=0;kk<4;kk++) aoff[kk] = ((2*kk + (lg>>1))*4 + (lr&3))*64 + (lr>>2)*16 + (lg&1)*8;
  u16* sw = sw_ + (wave<<11);
  for (int tile = blockIdx.x*4 + wave; tile < NTILES; tile += RGRID*4){
    const u16* ht = H + (long)tile*2048;
    bf16x8 a[4];
#pragma unroll
    for (int kk=0;kk<4;kk++) a[kk] = *(const bf16x8*)(ht + aoff[kk]);
    floatx4 acc[8];
#pragma unroll
    for (int i=0;i<8;i++) acc[i]=(floatx4){0,0,0,0};
#pragma unroll
    for (int kk=0;kk<4;kk++){
#pragma unroll
      for (int nt=0;nt<8;nt++){
        bf16x8 b = *(const bf16x8*)(W + ((kk*8+nt)*64 + lane)*8);
        acc[nt] = __builtin_amdgcn_mfma_f32_16x16x32_bf16(a[kk], b, acc[nt], 0, 0, 0);
      }
    }
    u16* xt = xb + (long)tile*2048;
#pragma unroll
    for (int r=0;r<4;r++){
#pragma unroll
      for (int nt=0;nt<8;nt++){
        int o = (nt*4+r)*64 + lane;           // full-line RMW in swizzled layout
        float v = acc[nt][r] + nb2v[nt] + b2f(xt[o]);
        acc[nt][r] = v;
        if (!LN) xt[o] = f2b(v);
      }
    }
    if (LN){
      float s[4] = {0,0,0,0}, q[4] = {0,0,0,0};
#pragma unroll
      for (int r=0;r<4;r++){
#pragma unroll
        for (int nt=0;nt<8;nt++){ float v = acc[nt][r]; s[r] += v; q[r] += v*v; }
      }
#pragma unroll
      for (int mask=1; mask<16; mask<<=1){
#pragma unroll
        for (int r=0;r<4;r++){ s[r] += __shfl_xor(s[r], mask); q[r] += __shfl_xor(q[r], mask); }
      }
      float mu4[4], inv4[4];
#pragma unroll
      for (int r=0;r<4;r++){
        float mu = s[r]*(1.f/128.f);
        float var = q[r]*(1.f/128.f) - mu*mu;
        mu4[r] = mu; inv4[r] = rsqrtf(var + 1e-5f);
      }
      if (isbf){
        // stage bf16 rows through LDS -> full-line row-major stores
#pragma unroll
        for (int r=0;r<4;r++){
#pragma unroll
          for (int nt=0;nt<8;nt++)
            sw[(lg*4+r)*128 + nt*16 + lr] = f2b((acc[nt][r]-mu4[r])*inv4[r]*gv[nt] + bvv[nt]);
        }
        u16* ot = (u16*)outp + (long)tile*2048;
#pragma unroll
        for (int j=0;j<4;j++){
          bf16x8 v = *(const bf16x8*)(sw + j*512 + lane*8);
          *(bf16x8*)(ot + j*512 + lane*8) = v;
        }
      } else {
#pragma unroll
        for (int r=0;r<4;r++){
          long row = (long)tile*16 + lg*4 + r;
#pragma unroll
          for (int nt=0;nt<8;nt++){
            int col = nt*16 + lr;
            ((float*)outp)[row*128+col] = (acc[nt][r]-mu4[r])*inv4[r]*gv[nt] + bvv[nt];
          }
        }
      }
    }
  }
}

// ---------- CSR aggregation: one wave per target node, chunked x4 (R5-proven) ----------
// A/B/Hb row-major (R0-proven addressing): row gather = 2 full 128B lines.
__global__ __launch_bounds__(256) void agg_kernel(
    const int* __restrict__ rowptr, const int* __restrict__ permsrc,
    const float* __restrict__ pf_in,
    const u16* __restrict__ A, const u16* __restrict__ B,
    const void* __restrict__ ew1, long w1c_off,
    const float* __restrict__ w2p, const float* __restrict__ c2pl,
    const float* __restrict__ pp,
    u16* __restrict__ Hb, float* __restrict__ pf_out, int N,
    const int* __restrict__ flagp)
{
  const int isbf = *flagp;
  int tid = threadIdx.x, lane = tid & 63;
  int t = blockIdx.x*4 + (tid>>6);
  if (t >= N) return;
  int tu = __builtin_amdgcn_readfirstlane(t);   // wave-uniform -> scalar loads
  float c0 = ldf(ew1, w1c_off + 2*lane,     isbf);
  float c1 = ldf(ew1, w1c_off + 2*lane + 1, isbf);
  float2 wp = *(const float2*)(w2p + 2*lane);
  float c2 = c2pl[0];
  float p0 = pp[0], p1 = pp[1], p2 = pp[2], p3 = pp[3];
  int jb = rowptr[tu], je = rowptr[tu+1];
  float2 pt = *(const float2*)(pf_in + 2*(long)tu);
  unsigned bv = *(const unsigned*)(B + (long)tu*128 + 2*lane);
  float b0 = b2f((u16)bv), b1 = b2f((u16)(bv>>16));
  float h0a = 0.f, h1a = 0.f, dpx = 0.f, dpy = 0.f;
  for (int j0 = jb; j0 < je; j0 += 4){
    int m = je - j0; if (m > 4) m = 4;
    int s[4]; float2 ps[4]; unsigned av[4];
    float part[4], dist[4], dxv[4], dyv[4];
#pragma unroll
    for (int c=0;c<4;c++) if (c<m) s[c] = permsrc[j0+c];
#pragma unroll
    for (int c=0;c<4;c++) if (c<m){
      ps[c] = *(const float2*)(pf_in + 2*(long)s[c]);
      av[c] = *(const unsigned*)(A + (long)s[c]*128 + 2*lane);
    }
#pragma unroll
    for (int c=0;c<4;c++){
      if (c<m){
        float dx = pt.x - ps[c].x, dy = pt.y - ps[c].y;
        float d2 = dx*dx + dy*dy;
        float dd = __builtin_amdgcn_sqrtf(d2);
        float h0 = siluf(b2f((u16)av[c])       + b0 + dd*c0);
        float h1 = siluf(b2f((u16)(av[c]>>16)) + b1 + dd*c1);
        h0a += h0; h1a += h1;
        part[c] = h0*wp.x + h1*wp.y;
        dist[c] = dd; dxv[c] = dx; dyv[c] = dy;
      } else part[c] = 0.f;
    }
#pragma unroll
    for (int off=32; off; off>>=1){
#pragma unroll
      for (int c=0;c<4;c++) part[c] += __shfl_xor(part[c], off);
    }
#pragma unroll
    for (int c=0;c<4;c++){
      if (c<m){
        float spre = part[c] + c2 + dist[c]*p0 + p1;
        float pwv  = siluf(spre)*p2 + p3;
        float inv  = __builtin_amdgcn_rcpf(dist[c] + 1e-6f);
        dpx += dxv[c]*inv*pwv; dpy += dyv[c]*inv*pwv;
      }
    }
  }
  *(unsigned*)(Hb + (long)tu*128 + 2*lane) = (unsigned)f2b(h0a) | ((unsigned)f2b(h1a)<<16);
  if (lane == 0){
    float2 o; o.x = pt.x + dpx; o.y = pt.y + dpy;
    *(float2*)(pf_out + 2*(long)tu) = o;
  }
}

extern "C" void kernel_launch(void* const* d_in, const int* in_sizes, int n_in,
                              void* d_out, int out_size, void* d_ws, size_t ws_size,
                              hipStream_t stream)
{
  const void* nf  = d_in[0];
  const void* pos = d_in[1];
  const void* npw = d_in[3];
  const void* npb = d_in[4];
  const void* ew1 = d_in[7];
  const void* eb1 = d_in[8];
  const void* ew2 = d_in[9];
  const void* eb2 = d_in[10];
  const void* nw1 = d_in[11];
  const void* nb1 = d_in[12];
  const void* nw2 = d_in[13];
  const void* nb2 = d_in[14];
  const void* pw1 = d_in[15];
  const void* pb1 = d_in[16];
  const void* pw2 = d_in[17];
  const void* pb2 = d_in[18];
  const void* lng = d_in[19];
  const void* lnb = d_in[20];
  const int* eidx = (const int*)d_in[21];
  const int N = NNODES, E = NEDGES;
  const int* srcp = eidx;
  const int* tgtp = eidx + E;

  char* w = (char*)d_ws;
  size_t off = 0;
  auto alloc = [&](size_t bytes)->char* { char* p = w + off; off += (bytes + 255)/256*256; return p; };
  u16*   xb    = (u16*)  alloc((size_t)N*128*2);
  u16*   Ab    = (u16*)  alloc((size_t)N*128*2);
  u16*   Bb    = (u16*)  alloc((size_t)N*128*2);
  u16*   Hb    = (u16*)  alloc((size_t)N*128*2);
  float* pf0   = (float*)alloc((size_t)N*2*4);
  float* pf1   = (float*)alloc((size_t)N*2*4);
  int*   cnt   = (int*)  alloc((size_t)N*4);
  int*   rowptr= (int*)  alloc((size_t)(N+1)*4);
  int*   cursor= (int*)  alloc((size_t)N*4);
  float* degf  = (float*)alloc((size_t)N*4);
  int*   perm  = (int*)  alloc((size_t)E*4);
  int*   bsum  = (int*)  alloc(256*4);
  u16*   pk    = (u16*)  alloc((size_t)28*16384*2);
  float* ebW   = (float*)alloc(4*128*4);
  float* w2p   = (float*)alloc(4*128*4);
  float* c2p   = (float*)alloc(4*4);
  float* pparm = (float*)alloc(16*4);
  int*   flag  = (int*)  alloc(4);
  u16* hb = Ab;   // Ab dead after agg_kernel; buffer reused (swizzled) for hb

  const int NB = (N + 255)/256;  // 196 <= 256
  detect_kernel<<<1, 64, 0, stream>>>(lng, flag);
  hipMemsetAsync(cnt, 0, (size_t)N*4, stream);
  hist_kernel<<<(E+255)/256, 256, 0, stream>>>(tgtp, cnt, E);
  bsum_kernel<<<NB, 256, 0, stream>>>(cnt, bsum, N);
  bscan_kernel<<<1, 256, 0, stream>>>(bsum, NB);
  csr_kernel<<<NB, 256, 0, stream>>>(cnt, bsum, rowptr, cursor, degf, N);
  scatter_kernel<<<(E+255)/256, 256, 0, stream>>>(srcp, tgtp, cursor, perm, E);
  setup_kernel<<<SU_END, 256, 0, stream>>>(
      ew1, ew2, nw1, nw2, pk,
      eb2, pw1, pb1, pw2, pb2,
      w2p, c2p, pparm, ebW,
      nf, npw, npb, xb,
      pos, pf0, flag);

  // layer 0 A/B from projected x
  mm_ab_kernel<<<MMGRID, 256, 0, stream>>>(xb, pk + 0*16384, pk + 1*16384,
                                           eb1, 0, Ab, Bb, flag);
  for (int l = 0; l < 4; l++){
    const u16* NW1a = pk + (l*6+3)*16384;
    const u16* NW2p = pk + (l*6+5)*16384;
    const u16* W12p = pk + (24+l)*16384;
    float* pin  = (l & 1) ? pf1 : pf0;
    float* pout = (l & 1) ? pf0 : pf1;

    agg_kernel<<<(N+3)/4, 256, 0, stream>>>(
        rowptr, perm, pin, Ab, Bb,
        ew1, (long)l*257*128 + 256*128,
        w2p + l*128, c2p + l, pparm + l*4,
        Hb, pout, N, flag);
    mm_hidden_kernel<<<MMGRID, 256, 0, stream>>>(
        xb, Hb, NW1a, W12p, nb1, (long)l*128, degf, ebW + l*128, hb, flag);
    if (l < 3){
      mm_res_kernel<0><<<RGRID, 256, 0, stream>>>(
          hb, NW2p, nb2, (long)l*128, xb, nullptr, nullptr, nullptr, flag);
      mm_ab_kernel<<<MMGRID, 256, 0, stream>>>(
          xb, pk + ((l+1)*6+0)*16384, pk + ((l+1)*6+1)*16384,
          eb1, (long)(l+1)*128, Ab, Bb, flag);
    } else {
      mm_res_kernel<1><<<RGRID, 256, 0, stream>>>(
          hb, NW2p, nb2, (long)l*128, xb, lng, lnb, d_out, flag);
    }
  }
}

// Round 7
// 459.471 us; speedup vs baseline: 2.5728x; 2.5728x over previous
//
#include <hip/hip_runtime.h>
#include <hip/hip_bf16.h>

// EGNN encoder, N=50000, E=250000, D=128, L=4. bf16 inputs/output (verified R2).
// R3: CSR-by-tgt aggregation.  R4: 3-stage CSR scan.  R5: agg chunked x4.
// R7: weight-stationary streaming matmuls.  R10: bf16 residual stream.
// R11: merged setup kernel. 524us.
// R12 FAILED: cooperative front-end (+350us, occupancy-starved).
// R13 FAILED: 512-thr mm blocks (scattered-2B store amplification exposed).
// R14: fragment-swizzled internal tensors (agg regressed). 563us.
// R15: split layouts per consumer; mm C-tiles staged through per-wave LDS. 518us.
// R16/R17 FAILED: weights from L1/L2 -> write-streams evict the 96KB weight set
//     from L2 (write-allocate), every weight read goes to HBM: mm kernels
//     22->101us, FETCH 88-99MB. LESSON: weight reuse must live in LDS.
// R18: revert to weight-in-LDS; two targeted changes:
//     (a) mm_ab split into 2x mm_single (32KB weights + 16KB stage = 48KB LDS
//         -> 3 blocks/CU = 3 waves/SIMD vs 2).
//     (b) mm_hidden+mm_res fused into mega kernel (512thr, 96KB weights +
//         34KB stage = 130KB dynamic LDS): h stays on-chip (C-frag -> per-wave
//         LDS stage -> A-frag), saving the 25.6MB hb roundtrip + 1 dispatch/layer.

#define NNODES 50000
#define NEDGES 250000
#define NTILES 3125   // 50000/16 exactly, no tail
#define SGRID  768    // mm_single: 768 blocks x 4 waves, 3 blocks/CU co-resident
#define MGRID  256    // mega: 256 blocks x 8 waves, 1 block/CU

typedef unsigned short u16;
typedef __attribute__((ext_vector_type(8))) short bf16x8;
typedef __attribute__((ext_vector_type(4))) float floatx4;

__device__ __forceinline__ float b2f(u16 h){ unsigned u=((unsigned)h)<<16; float f; __builtin_memcpy(&f,&u,4); return f; }
__device__ __forceinline__ u16 f2b(float f){ unsigned u; __builtin_memcpy(&u,&f,4); u = u + 0x7FFFu + ((u>>16)&1u); return (u16)(u>>16); }
__device__ __forceinline__ float siluf(float x){ return x*__builtin_amdgcn_rcpf(1.f+__expf(-x)); }
__device__ __forceinline__ float ldf(const void* p, long i, int isbf){
  return isbf ? b2f(((const u16*)p)[i]) : ((const float*)p)[i];
}
// swizzled element offset for MFMA-internal N x 128 tensors (xb):
__device__ __forceinline__ long swz(long row, int col){
  return (row>>4)*2048 + (long)(((col>>4)*4 + (int)(row&3))*64 + (((int)(row&15))>>2)*16 + (col&15));
}

__global__ void detect_kernel(const void* lng, int* flag){
  if (threadIdx.x==0 && blockIdx.x==0) *flag = (((const u16*)lng)[0] != 0) ? 1 : 0;
}

// ---------- merged setup: phases partitioned by blockIdx ----------
#define SU_W12   192
#define SU_EBW   704
#define SU_W2P   708
#define SU_PPARM 712
#define SU_PROJ  713
#define SU_CVTP  25713
#define SU_END   26104
__global__ __launch_bounds__(256) void setup_kernel(
    const void* __restrict__ ew1, const void* __restrict__ ew2,
    const void* __restrict__ nw1, const void* __restrict__ nw2,
    u16* __restrict__ packed,
    const void* __restrict__ eb2, const void* __restrict__ pw1,
    const void* __restrict__ pb1, const void* __restrict__ pw2v, const void* __restrict__ pb2,
    float* __restrict__ w2p, float* __restrict__ c2p, float* __restrict__ pparm,
    float* __restrict__ ebW,
    const void* __restrict__ nf, const void* __restrict__ npw, const void* __restrict__ npb,
    u16* __restrict__ xb,
    const void* __restrict__ pos, float* __restrict__ pf,
    const int* __restrict__ flagp)
{
  const int isbf = *flagp;
  const int b = blockIdx.x, tid = threadIdx.x;
  __shared__ float red[128];
  if (b < SU_W12){
    int t = b*256 + tid;
    int m = t >> 11; int r = t & 2047;
    int lane = r & 63; int ntk = r >> 6;
    int kk = ntk >> 3, nt = ntk & 7;
    int l = m/6, w = m%6;
    const void* src; long off;
    switch(w){
      case 0: src=ew1; off=(long)l*257*128;            break; // W1a
      case 1: src=ew1; off=(long)l*257*128 + 128*128;  break; // W1b
      case 2: src=ew2; off=(long)l*128*128;            break; // EW2 (layout slot)
      case 3: src=nw1; off=(long)l*256*128;            break; // NW1a
      case 4: src=nw1; off=(long)l*256*128 + 128*128;  break; // NW1b (unused)
      default:src=nw2; off=(long)l*128*128;            break; // NW2
    }
    int c  = nt*16 + (lane & 15);
    int k0 = kk*32 + (lane >> 4)*8;
    u16 vals[8];
#pragma unroll
    for (int j=0;j<8;j++){
      long idx = off + (long)(k0+j)*128 + c;
      vals[j] = isbf ? ((const u16*)src)[idx] : f2b(((const float*)src)[idx]);
    }
    bf16x8 v; __builtin_memcpy(&v, vals, 16);
    *(bf16x8*)(packed + (long)t*8) = v;
  } else if (b < SU_EBW){
    int bb = b - SU_W12;
    int l = bb >> 7, k = bb & 127;
    if (tid < 128){
      int j = tid;
      long e2 = (long)l*16384 + (long)k*128;
      long nb = (long)l*256*128 + 128*128;
      float acc = 0.f;
      for (int d=0; d<128; d++)
        acc += ldf(ew2, e2 + d, isbf) * ldf(nw1, nb + (long)d*128 + j, isbf);
      int kk = k>>5, lane = ((k>>3)&3)*16 + (j&15), nt = j>>4, jj = k&7;
      packed[(long)(24+l)*16384 + (long)((kk*8+nt)*64 + lane)*8 + jj] = f2b(acc);
    }
  } else if (b < SU_W2P){
    int l = b - SU_EBW;
    if (tid < 128){
      int j = tid;
      long nb = (long)l*256*128 + 128*128;
      float acc = 0.f;
      for (int d=0; d<128; d++)
        acc += ldf(eb2, (long)l*128 + d, isbf) * ldf(nw1, nb + (long)d*128 + j, isbf);
      ebW[l*128+j] = acc;
    }
  } else if (b < SU_PPARM){
    int l = b - SU_W2P;
    int i = tid;
    long Woff = (long)l*128*128, poff = (long)l*129;
    if (i < 128){
      float acc = 0.f;
      for (int j=0;j<128;j++) acc += ldf(ew2, Woff + (long)i*128 + j, isbf) * ldf(pw1, poff + j, isbf);
      w2p[l*128+i] = acc;
      red[i] = ldf(eb2, (long)l*128 + i, isbf) * ldf(pw1, poff + i, isbf);
    }
    __syncthreads();
    for (int st=64; st>0; st>>=1){ if (i<st) red[i]+=red[i+st]; __syncthreads(); }
    if (i==0) c2p[l] = red[0];
  } else if (b == SU_PPARM){
    int l = tid;
    if (l < 4){
      pparm[l*4+0] = ldf(pw1, (long)l*129 + 128, isbf);
      pparm[l*4+1] = ldf(pb1, l, isbf);
      pparm[l*4+2] = ldf(pw2v, l, isbf);
      pparm[l*4+3] = ldf(pb2, l, isbf);
    }
  } else if (b < SU_CVTP){
    int n = (b - SU_PROJ)*2 + (tid>>7), d = tid & 127;
    if (n < NNODES){
      float acc = ldf(npb, d, isbf);
#pragma unroll
      for (int f=0; f<12; f++) acc += ldf(nf, (long)n*12+f, isbf) * ldf(npw, f*128+d, isbf);
      xb[swz(n, d)] = f2b(acc);   // swizzled residual layout
    }
  } else {
    int i = (b - SU_CVTP)*256 + tid;
    if (i < 2*NNODES) pf[i] = ldf(pos, i, isbf);
  }
}

// ---------- CSR build: histogram, 3-stage scan, scatter ----------
__global__ __launch_bounds__(256) void hist_kernel(const int* __restrict__ tgt, int* __restrict__ cnt, int E){
  int i = blockIdx.x*256 + threadIdx.x;
  if (i < E) atomicAdd(&cnt[tgt[i]], 1);
}

__global__ __launch_bounds__(256) void bsum_kernel(const int* __restrict__ cnt, int* __restrict__ bsum, int N){
  int i = blockIdx.x*256 + threadIdx.x;
  int v = (i < N) ? cnt[i] : 0;
#pragma unroll
  for (int off=32; off; off>>=1) v += __shfl_down(v, off);
  __shared__ int ws[4];
  if ((threadIdx.x & 63) == 0) ws[threadIdx.x>>6] = v;
  __syncthreads();
  if (threadIdx.x == 0) bsum[blockIdx.x] = ws[0]+ws[1]+ws[2]+ws[3];
}

__global__ __launch_bounds__(256) void bscan_kernel(int* __restrict__ bsum, int nb){
  __shared__ int lds[256];
  int i = threadIdx.x;
  int v = (i < nb) ? bsum[i] : 0;
  lds[i] = v; __syncthreads();
#pragma unroll
  for (int off=1; off<256; off<<=1){
    int t = (i>=off)? lds[i-off] : 0; __syncthreads();
    lds[i] += t; __syncthreads();
  }
  if (i < nb) bsum[i] = lds[i] - v;  // exclusive prefix
}

__global__ __launch_bounds__(256) void csr_kernel(
    const int* __restrict__ cnt, const int* __restrict__ bsum,
    int* __restrict__ rowptr, int* __restrict__ cursor, float* __restrict__ degf, int N)
{
  __shared__ int lds[256];
  int i = blockIdx.x*256 + threadIdx.x;
  int c = (i < N) ? cnt[i] : 0;
  lds[threadIdx.x] = c; __syncthreads();
#pragma unroll
  for (int off=1; off<256; off<<=1){
    int t = (threadIdx.x>=off)? lds[threadIdx.x-off] : 0; __syncthreads();
    lds[threadIdx.x] += t; __syncthreads();
  }
  int run = bsum[blockIdx.x] + lds[threadIdx.x] - c;  // exclusive
  if (i < N){
    rowptr[i] = run; cursor[i] = run; degf[i] = (float)c;
    if (i == N-1) rowptr[N] = run + c;
  }
}

__global__ __launch_bounds__(256) void scatter_kernel(
    const int* __restrict__ src, const int* __restrict__ tgt,
    int* __restrict__ cursor, int* __restrict__ permsrc, int E)
{
  int e = blockIdx.x*256 + threadIdx.x;
  if (e >= E) return;
  int t = tgt[e];
  int p = atomicAdd(&cursor[t], 1);
  permsrc[p] = src[e];
}

// ---------- single streaming matmul: Out = bf16(x@W [+ bias]) ----------
// X swizzled; W packed in LDS (32KB); Out row-major via per-wave 4KB LDS stage.
// LDS total 48KB -> 3 blocks/CU = 3 waves/SIMD.
__global__ __launch_bounds__(256, 3) void mm_single_kernel(
    const u16* __restrict__ X, const u16* __restrict__ W,
    const void* __restrict__ bias, long bias_off, int hasbias,
    u16* __restrict__ Out, const int* __restrict__ flagp)
{
  extern __shared__ u16 dls[];
  u16* wl = dls;                         // 16384 u16 = 32KB
  const int tid = threadIdx.x, wave = tid>>6, lane = tid&63;
  const int isbf = *flagp;
  const int lr = lane&15, lg = lane>>4;
  u16* sw = dls + 16384 + (wave<<11);    // per-wave 2048 u16 = 4KB
  for (int i=tid; i<2048; i+=256)
    *(bf16x8*)(wl + (long)i*8) = *(const bf16x8*)(W + (long)i*8);
  float biasv[8];
#pragma unroll
  for (int nt=0;nt<8;nt++) biasv[nt] = hasbias ? ldf(bias, bias_off + nt*16 + lr, isbf) : 0.f;
  int aoff[4];
#pragma unroll
  for (int kk=0;kk<4;kk++) aoff[kk] = ((2*kk + (lg>>1))*4 + (lr&3))*64 + (lr>>2)*16 + (lg&1)*8;
  __syncthreads();
  for (int tile = blockIdx.x*4 + wave; tile < NTILES; tile += SGRID*4){
    const u16* xt = X + (long)tile*2048;
    bf16x8 a[4];
#pragma unroll
    for (int kk=0;kk<4;kk++) a[kk] = *(const bf16x8*)(xt + aoff[kk]);
    floatx4 acc[8];
#pragma unroll
    for (int i=0;i<8;i++) acc[i]=(floatx4){0,0,0,0};
#pragma unroll
    for (int kk=0;kk<4;kk++){
#pragma unroll
      for (int nt=0;nt<8;nt++){
        bf16x8 b = *(const bf16x8*)(wl + ((kk*8+nt)*64 + lane)*8);
        acc[nt] = __builtin_amdgcn_mfma_f32_16x16x32_bf16(a[kk], b, acc[nt], 0, 0, 0);
      }
    }
    u16* ot = Out + (long)tile*2048;
#pragma unroll
    for (int r=0;r<4;r++){
#pragma unroll
      for (int nt=0;nt<8;nt++) sw[(lg*4+r)*128 + nt*16 + lr] = f2b(acc[nt][r] + biasv[nt]);
    }
#pragma unroll
    for (int j=0;j<4;j++){
      bf16x8 v = *(const bf16x8*)(sw + j*512 + lane*8);
      *(bf16x8*)(ot + j*512 + lane*8) = v;
    }
  }
}

// ---------- mega: h = silu(xb@NW1a + Hb@W12 + deg*ebW + nb1); res = xb + h@NW2 + nb2 ----------
// 512 threads, 8 waves. LDS: W1(32K) + W12(32K) + W2(32K) + 8x per-wave stage
// (2176 u16, row stride 136 = 272B, 16B-aligned) = 130KB -> 1 block/CU.
// h never touches HBM: C-frags -> LDS stage -> A-frags (per-wave, DS in-order).
// X and xb alias (same buffer, no __restrict__): each tile owned by one wave.
template<int LN>
__global__ __launch_bounds__(512, 2) void mega_kernel(
    const u16* X, const u16* __restrict__ H,
    const u16* __restrict__ W1, const u16* __restrict__ W12, const u16* __restrict__ W2,
    const void* __restrict__ nb1, long nb1_off,
    const void* __restrict__ nb2, long nb2_off,
    const float* __restrict__ degf, const float* __restrict__ ebW,
    u16* xb,
    const void* __restrict__ lng, const void* __restrict__ lnb, void* __restrict__ outp,
    const int* __restrict__ flagp)
{
  extern __shared__ u16 dls[];
  u16* w1s  = dls;
  u16* w12s = dls + 16384;
  u16* w2s  = dls + 32768;
  const int tid = threadIdx.x, wave = tid>>6, lane = tid&63;
  const int isbf = *flagp;
  const int lr = lane&15, lg = lane>>4;
  u16* stg = dls + 49152 + wave*2176;
  for (int i=tid; i<2048; i+=512){
    *(bf16x8*)(w1s  + (long)i*8) = *(const bf16x8*)(W1  + (long)i*8);
    *(bf16x8*)(w12s + (long)i*8) = *(const bf16x8*)(W12 + (long)i*8);
    *(bf16x8*)(w2s  + (long)i*8) = *(const bf16x8*)(W2  + (long)i*8);
  }
  float nb1v[8], nb2v[8], ebv[8];
#pragma unroll
  for (int nt=0;nt<8;nt++){
    int col = nt*16 + lr;
    nb1v[nt] = ldf(nb1, nb1_off + col, isbf);
    nb2v[nt] = ldf(nb2, nb2_off + col, isbf);
    ebv[nt]  = ebW[col];
  }
  float gv[8], bvv[8];
  if (LN){
#pragma unroll
    for (int nt=0;nt<8;nt++){ int col=nt*16+lr; gv[nt]=ldf(lng,col,isbf); bvv[nt]=ldf(lnb,col,isbf); }
  }
  int aoff[4];
#pragma unroll
  for (int kk=0;kk<4;kk++) aoff[kk] = ((2*kk + (lg>>1))*4 + (lr&3))*64 + (lr>>2)*16 + (lg&1)*8;
  __syncthreads();
  for (int tile = blockIdx.x*8 + wave; tile < NTILES; tile += MGRID*8){
    // ---- phase 1: hidden pre-activation ----
    const u16* xt = X + (long)tile*2048;
    const u16* hr = H + ((long)tile*16 + lr)*128;   // row-major Hb
    bf16x8 ax[4], ah[4];
#pragma unroll
    for (int kk=0;kk<4;kk++){
      ax[kk] = *(const bf16x8*)(xt + aoff[kk]);
      ah[kk] = *(const bf16x8*)(hr + kk*32 + lg*8);
    }
    floatx4 acc[8];
#pragma unroll
    for (int i=0;i<8;i++) acc[i]=(floatx4){0,0,0,0};
#pragma unroll
    for (int kk=0;kk<4;kk++){
#pragma unroll
      for (int nt=0;nt<8;nt++){
        bf16x8 b1 = *(const bf16x8*)(w1s + ((kk*8+nt)*64 + lane)*8);
        acc[nt] = __builtin_amdgcn_mfma_f32_16x16x32_bf16(ax[kk], b1, acc[nt], 0, 0, 0);
        bf16x8 b2 = *(const bf16x8*)(w12s + ((kk*8+nt)*64 + lane)*8);
        acc[nt] = __builtin_amdgcn_mfma_f32_16x16x32_bf16(ah[kk], b2, acc[nt], 0, 0, 0);
      }
    }
    float dv[4];
#pragma unroll
    for (int r=0;r<4;r++) dv[r] = degf[(long)tile*16 + lg*4 + r];
    // ---- stage h: C-frag -> row-major LDS (stride 136 = 272B, 16B aligned) ----
#pragma unroll
    for (int r=0;r<4;r++){
#pragma unroll
      for (int nt=0;nt<8;nt++)
        stg[(lg*4+r)*136 + nt*16 + lr] = f2b(siluf(acc[nt][r] + nb1v[nt] + dv[r]*ebv[nt]));
    }
    // ---- phase 2: h @ NW2 (A-frags from stage; per-wave DS in-order) ----
    bf16x8 ha[4];
#pragma unroll
    for (int kk=0;kk<4;kk++) ha[kk] = *(const bf16x8*)(stg + lr*136 + kk*32 + lg*8);
    floatx4 acc2[8];
#pragma unroll
    for (int i=0;i<8;i++) acc2[i]=(floatx4){0,0,0,0};
#pragma unroll
    for (int kk=0;kk<4;kk++){
#pragma unroll
      for (int nt=0;nt<8;nt++){
        bf16x8 b = *(const bf16x8*)(w2s + ((kk*8+nt)*64 + lane)*8);
        acc2[nt] = __builtin_amdgcn_mfma_f32_16x16x32_bf16(ha[kk], b, acc2[nt], 0, 0, 0);
      }
    }
    // ---- residual ----
    u16* xo = xb + (long)tile*2048;
#pragma unroll
    for (int r=0;r<4;r++){
#pragma unroll
      for (int nt=0;nt<8;nt++){
        int o = (nt*4+r)*64 + lane;           // full-line swizzled RMW
        float v = acc2[nt][r] + nb2v[nt] + b2f(xo[o]);
        acc2[nt][r] = v;
        if (!LN) xo[o] = f2b(v);
      }
    }
    if (LN){
      float s[4] = {0,0,0,0}, q[4] = {0,0,0,0};
#pragma unroll
      for (int r=0;r<4;r++){
#pragma unroll
        for (int nt=0;nt<8;nt++){ float v = acc2[nt][r]; s[r] += v; q[r] += v*v; }
      }
#pragma unroll
      for (int mask=1; mask<16; mask<<=1){
#pragma unroll
        for (int r=0;r<4;r++){ s[r] += __shfl_xor(s[r], mask); q[r] += __shfl_xor(q[r], mask); }
      }
      float mu4[4], inv4[4];
#pragma unroll
      for (int r=0;r<4;r++){
        float mu = s[r]*(1.f/128.f);
        float var = q[r]*(1.f/128.f) - mu*mu;
        mu4[r] = mu; inv4[r] = rsqrtf(var + 1e-5f);
      }
      if (isbf){
        // reuse stage (h frags already consumed) with 128-stride for contiguous rows
#pragma unroll
        for (int r=0;r<4;r++){
#pragma unroll
          for (int nt=0;nt<8;nt++)
            stg[(lg*4+r)*128 + nt*16 + lr] = f2b((acc2[nt][r]-mu4[r])*inv4[r]*gv[nt] + bvv[nt]);
        }
        u16* ot = (u16*)outp + (long)tile*2048;
#pragma unroll
        for (int j=0;j<4;j++){
          bf16x8 v = *(const bf16x8*)(stg + j*512 + lane*8);
          *(bf16x8*)(ot + j*512 + lane*8) = v;
        }
      } else {
#pragma unroll
        for (int r=0;r<4;r++){
          long row = (long)tile*16 + lg*4 + r;
#pragma unroll
          for (int nt=0;nt<8;nt++){
            int col = nt*16 + lr;
            ((float*)outp)[row*128+col] = (acc2[nt][r]-mu4[r])*inv4[r]*gv[nt] + bvv[nt];
          }
        }
      }
    }
  }
}

// ---------- CSR aggregation: one wave per target node, chunked x4 (R5-proven) ----------
__global__ __launch_bounds__(256) void agg_kernel(
    const int* __restrict__ rowptr, const int* __restrict__ permsrc,
    const float* __restrict__ pf_in,
    const u16* __restrict__ A, const u16* __restrict__ B,
    const void* __restrict__ ew1, long w1c_off,
    const float* __restrict__ w2p, const float* __restrict__ c2pl,
    const float* __restrict__ pp,
    u16* __restrict__ Hb, float* __restrict__ pf_out, int N,
    const int* __restrict__ flagp)
{
  const int isbf = *flagp;
  int tid = threadIdx.x, lane = tid & 63;
  int t = blockIdx.x*4 + (tid>>6);
  if (t >= N) return;
  int tu = __builtin_amdgcn_readfirstlane(t);   // wave-uniform -> scalar loads
  float c0 = ldf(ew1, w1c_off + 2*lane,     isbf);
  float c1 = ldf(ew1, w1c_off + 2*lane + 1, isbf);
  float2 wp = *(const float2*)(w2p + 2*lane);
  float c2 = c2pl[0];
  float p0 = pp[0], p1 = pp[1], p2 = pp[2], p3 = pp[3];
  int jb = rowptr[tu], je = rowptr[tu+1];
  float2 pt = *(const float2*)(pf_in + 2*(long)tu);
  unsigned bv = *(const unsigned*)(B + (long)tu*128 + 2*lane);
  float b0 = b2f((u16)bv), b1 = b2f((u16)(bv>>16));
  float h0a = 0.f, h1a = 0.f, dpx = 0.f, dpy = 0.f;
  for (int j0 = jb; j0 < je; j0 += 4){
    int m = je - j0; if (m > 4) m = 4;
    int s[4]; float2 ps[4]; unsigned av[4];
    float part[4], dist[4], dxv[4], dyv[4];
#pragma unroll
    for (int c=0;c<4;c++) if (c<m) s[c] = permsrc[j0+c];
#pragma unroll
    for (int c=0;c<4;c++) if (c<m){
      ps[c] = *(const float2*)(pf_in + 2*(long)s[c]);
      av[c] = *(const unsigned*)(A + (long)s[c]*128 + 2*lane);
    }
#pragma unroll
    for (int c=0;c<4;c++){
      if (c<m){
        float dx = pt.x - ps[c].x, dy = pt.y - ps[c].y;
        float d2 = dx*dx + dy*dy;
        float dd = __builtin_amdgcn_sqrtf(d2);
        float h0 = siluf(b2f((u16)av[c])       + b0 + dd*c0);
        float h1 = siluf(b2f((u16)(av[c]>>16)) + b1 + dd*c1);
        h0a += h0; h1a += h1;
        part[c] = h0*wp.x + h1*wp.y;
        dist[c] = dd; dxv[c] = dx; dyv[c] = dy;
      } else part[c] = 0.f;
    }
#pragma unroll
    for (int off=32; off; off>>=1){
#pragma unroll
      for (int c=0;c<4;c++) part[c] += __shfl_xor(part[c], off);
    }
#pragma unroll
    for (int c=0;c<4;c++){
      if (c<m){
        float spre = part[c] + c2 + dist[c]*p0 + p1;
        float pwv  = siluf(spre)*p2 + p3;
        float inv  = __builtin_amdgcn_rcpf(dist[c] + 1e-6f);
        dpx += dxv[c]*inv*pwv; dpy += dyv[c]*inv*pwv;
      }
    }
  }
  *(unsigned*)(Hb + (long)tu*128 + 2*lane) = (unsigned)f2b(h0a) | ((unsigned)f2b(h1a)<<16);
  if (lane == 0){
    float2 o; o.x = pt.x + dpx; o.y = pt.y + dpy;
    *(float2*)(pf_out + 2*(long)tu) = o;
  }
}

extern "C" void kernel_launch(void* const* d_in, const int* in_sizes, int n_in,
                              void* d_out, int out_size, void* d_ws, size_t ws_size,
                              hipStream_t stream)
{
  const void* nf  = d_in[0];
  const void* pos = d_in[1];
  const void* npw = d_in[3];
  const void* npb = d_in[4];
  const void* ew1 = d_in[7];
  const void* eb1 = d_in[8];
  const void* ew2 = d_in[9];
  const void* eb2 = d_in[10];
  const void* nw1 = d_in[11];
  const void* nb1 = d_in[12];
  const void* nw2 = d_in[13];
  const void* nb2 = d_in[14];
  const void* pw1 = d_in[15];
  const void* pb1 = d_in[16];
  const void* pw2 = d_in[17];
  const void* pb2 = d_in[18];
  const void* lng = d_in[19];
  const void* lnb = d_in[20];
  const int* eidx = (const int*)d_in[21];
  const int N = NNODES, E = NEDGES;
  const int* srcp = eidx;
  const int* tgtp = eidx + E;

  char* w = (char*)d_ws;
  size_t off = 0;
  auto alloc = [&](size_t bytes)->char* { char* p = w + off; off += (bytes + 255)/256*256; return p; };
  u16*   xb    = (u16*)  alloc((size_t)N*128*2);
  u16*   Ab    = (u16*)  alloc((size_t)N*128*2);
  u16*   Bb    = (u16*)  alloc((size_t)N*128*2);
  u16*   Hb    = (u16*)  alloc((size_t)N*128*2);
  float* pf0   = (float*)alloc((size_t)N*2*4);
  float* pf1   = (float*)alloc((size_t)N*2*4);
  int*   cnt   = (int*)  alloc((size_t)N*4);
  int*   rowptr= (int*)  alloc((size_t)(N+1)*4);
  int*   cursor= (int*)  alloc((size_t)N*4);
  float* degf  = (float*)alloc((size_t)N*4);
  int*   perm  = (int*)  alloc((size_t)E*4);
  int*   bsum  = (int*)  alloc(256*4);
  u16*   pk    = (u16*)  alloc((size_t)28*16384*2);
  float* ebW   = (float*)alloc(4*128*4);
  float* w2p   = (float*)alloc(4*128*4);
  float* c2p   = (float*)alloc(4*4);
  float* pparm = (float*)alloc(16*4);
  int*   flag  = (int*)  alloc(4);

  const int NB = (N + 255)/256;  // 196 <= 256
  detect_kernel<<<1, 64, 0, stream>>>(lng, flag);
  hipMemsetAsync(cnt, 0, (size_t)N*4, stream);
  hist_kernel<<<(E+255)/256, 256, 0, stream>>>(tgtp, cnt, E);
  bsum_kernel<<<NB, 256, 0, stream>>>(cnt, bsum, N);
  bscan_kernel<<<1, 256, 0, stream>>>(bsum, NB);
  csr_kernel<<<NB, 256, 0, stream>>>(cnt, bsum, rowptr, cursor, degf, N);
  scatter_kernel<<<(E+255)/256, 256, 0, stream>>>(srcp, tgtp, cursor, perm, E);
  setup_kernel<<<SU_END, 256, 0, stream>>>(
      ew1, ew2, nw1, nw2, pk,
      eb2, pw1, pb1, pw2, pb2,
      w2p, c2p, pparm, ebW,
      nf, npw, npb, xb,
      pos, pf0, flag);

  // layer 0 A/B from projected x (split kernels: 48KB LDS -> 3 blocks/CU)
  mm_single_kernel<<<SGRID, 256, 49152, stream>>>(xb, pk + 0*16384, eb1, 0, 1, Ab, flag);
  mm_single_kernel<<<SGRID, 256, 49152, stream>>>(xb, pk + 1*16384, nullptr, 0, 0, Bb, flag);
  for (int l = 0; l < 4; l++){
    const u16* NW1a = pk + (l*6+3)*16384;
    const u16* NW2p = pk + (l*6+5)*16384;
    const u16* W12p = pk + (24+l)*16384;
    float* pin  = (l & 1) ? pf1 : pf0;
    float* pout = (l & 1) ? pf0 : pf1;

    agg_kernel<<<(N+3)/4, 256, 0, stream>>>(
        rowptr, perm, pin, Ab, Bb,
        ew1, (long)l*257*128 + 256*128,
        w2p + l*128, c2p + l, pparm + l*4,
        Hb, pout, N, flag);
    if (l < 3){
      mega_kernel<0><<<MGRID, 512, 133120, stream>>>(
          xb, Hb, NW1a, W12p, NW2p, nb1, (long)l*128, nb2, (long)l*128,
          degf, ebW + l*128, xb, nullptr, nullptr, nullptr, flag);
      mm_single_kernel<<<SGRID, 256, 49152, stream>>>(
          xb, pk + ((l+1)*6+0)*16384, eb1, (long)(l+1)*128, 1, Ab, flag);
      mm_single_kernel<<<SGRID, 256, 49152, stream>>>(
          xb, pk + ((l+1)*6+1)*16384, nullptr, 0, 0, Bb, flag);
    } else {
      mega_kernel<1><<<MGRID, 512, 133120, stream>>>(
          xb, Hb, NW1a, W12p, NW2p, nb1, (long)l*128, nb2, (long)l*128,
          degf, ebW + l*128, xb, lng, lnb, d_out, flag);
    }
  }
}

// Round 8
// 446.620 us; speedup vs baseline: 2.6468x; 1.0288x over previous
//
#include <hip/hip_runtime.h>
#include <hip/hip_bf16.h>

// EGNN encoder, N=50000, E=250000, D=128, L=4. bf16 inputs/output (verified R2).
// R3: CSR-by-tgt aggregation.  R4: 3-stage CSR scan.  R5: agg chunked x4.
// R7: weight-stationary streaming matmuls.  R10: bf16 residual stream.
// R11: merged setup kernel. 524us.
// R12 FAILED: cooperative front-end (+350us, occupancy-starved).
// R13 FAILED: 512-thr mm blocks (scattered-2B store amplification exposed).
// R14: fragment-swizzled internal tensors (agg regressed). 563us.
// R15: split layouts per consumer; mm C-tiles staged through per-wave LDS. 518us.
// R16/R17 FAILED: weights from L1/L2 -> write-streams evict weights from L2;
//     every weight read -> HBM. LESSON: weight reuse must live in LDS.
// R18: (a) mm_ab -> 2x mm_single (48KB LDS, 3 blocks/CU); (b) mm_hidden+mm_res
//     fused into mega (h stays on-chip via per-wave LDS stage). 459us.
//     agg now 4x45us = 39% of total; trans-pipe-bound (32 trans-instr/chunk,
//     half redundant edge-scalar work replicated across all 64 lanes).
// R19: agg packed-scalar phase: lane group (lane&3) computes edge scalars
//     (sqrt/pwv-exp/rcp/inv-rcp 4x -> 1x each; dd re-broadcast via readlane);
//     persistent waves (2048 blocks, grid-stride) hoist per-node constant loads
//     and kill 12.5k-block dispatch churn.

#define NNODES 50000
#define NEDGES 250000
#define NTILES 3125   // 50000/16 exactly, no tail
#define SGRID  768    // mm_single: 768 blocks x 4 waves, 3 blocks/CU co-resident
#define MGRID  256    // mega: 256 blocks x 8 waves, 1 block/CU
#define AGGRID 2048   // agg: persistent, 8 blocks/CU, 32 waves/CU
#define AGWAVES (AGGRID*4)

typedef unsigned short u16;
typedef __attribute__((ext_vector_type(8))) short bf16x8;
typedef __attribute__((ext_vector_type(4))) float floatx4;

__device__ __forceinline__ float b2f(u16 h){ unsigned u=((unsigned)h)<<16; float f; __builtin_memcpy(&f,&u,4); return f; }
__device__ __forceinline__ u16 f2b(float f){ unsigned u; __builtin_memcpy(&u,&f,4); u = u + 0x7FFFu + ((u>>16)&1u); return (u16)(u>>16); }
__device__ __forceinline__ float siluf(float x){ return x*__builtin_amdgcn_rcpf(1.f+__expf(-x)); }
__device__ __forceinline__ float ldf(const void* p, long i, int isbf){
  return isbf ? b2f(((const u16*)p)[i]) : ((const float*)p)[i];
}
__device__ __forceinline__ float rdlane(float v, int l){
  int i; __builtin_memcpy(&i,&v,4);
  int r = __builtin_amdgcn_readlane(i, l);
  float f; __builtin_memcpy(&f,&r,4);
  return f;
}
// swizzled element offset for MFMA-internal N x 128 tensors (xb):
__device__ __forceinline__ long swz(long row, int col){
  return (row>>4)*2048 + (long)(((col>>4)*4 + (int)(row&3))*64 + (((int)(row&15))>>2)*16 + (col&15));
}

__global__ void detect_kernel(const void* lng, int* flag){
  if (threadIdx.x==0 && blockIdx.x==0) *flag = (((const u16*)lng)[0] != 0) ? 1 : 0;
}

// ---------- merged setup: phases partitioned by blockIdx ----------
#define SU_W12   192
#define SU_EBW   704
#define SU_W2P   708
#define SU_PPARM 712
#define SU_PROJ  713
#define SU_CVTP  25713
#define SU_END   26104
__global__ __launch_bounds__(256) void setup_kernel(
    const void* __restrict__ ew1, const void* __restrict__ ew2,
    const void* __restrict__ nw1, const void* __restrict__ nw2,
    u16* __restrict__ packed,
    const void* __restrict__ eb2, const void* __restrict__ pw1,
    const void* __restrict__ pb1, const void* __restrict__ pw2v, const void* __restrict__ pb2,
    float* __restrict__ w2p, float* __restrict__ c2p, float* __restrict__ pparm,
    float* __restrict__ ebW,
    const void* __restrict__ nf, const void* __restrict__ npw, const void* __restrict__ npb,
    u16* __restrict__ xb,
    const void* __restrict__ pos, float* __restrict__ pf,
    const int* __restrict__ flagp)
{
  const int isbf = *flagp;
  const int b = blockIdx.x, tid = threadIdx.x;
  __shared__ float red[128];
  if (b < SU_W12){
    int t = b*256 + tid;
    int m = t >> 11; int r = t & 2047;
    int lane = r & 63; int ntk = r >> 6;
    int kk = ntk >> 3, nt = ntk & 7;
    int l = m/6, w = m%6;
    const void* src; long off;
    switch(w){
      case 0: src=ew1; off=(long)l*257*128;            break; // W1a
      case 1: src=ew1; off=(long)l*257*128 + 128*128;  break; // W1b
      case 2: src=ew2; off=(long)l*128*128;            break; // EW2 (layout slot)
      case 3: src=nw1; off=(long)l*256*128;            break; // NW1a
      case 4: src=nw1; off=(long)l*256*128 + 128*128;  break; // NW1b (unused)
      default:src=nw2; off=(long)l*128*128;            break; // NW2
    }
    int c  = nt*16 + (lane & 15);
    int k0 = kk*32 + (lane >> 4)*8;
    u16 vals[8];
#pragma unroll
    for (int j=0;j<8;j++){
      long idx = off + (long)(k0+j)*128 + c;
      vals[j] = isbf ? ((const u16*)src)[idx] : f2b(((const float*)src)[idx]);
    }
    bf16x8 v; __builtin_memcpy(&v, vals, 16);
    *(bf16x8*)(packed + (long)t*8) = v;
  } else if (b < SU_EBW){
    int bb = b - SU_W12;
    int l = bb >> 7, k = bb & 127;
    if (tid < 128){
      int j = tid;
      long e2 = (long)l*16384 + (long)k*128;
      long nb = (long)l*256*128 + 128*128;
      float acc = 0.f;
      for (int d=0; d<128; d++)
        acc += ldf(ew2, e2 + d, isbf) * ldf(nw1, nb + (long)d*128 + j, isbf);
      int kk = k>>5, lane = ((k>>3)&3)*16 + (j&15), nt = j>>4, jj = k&7;
      packed[(long)(24+l)*16384 + (long)((kk*8+nt)*64 + lane)*8 + jj] = f2b(acc);
    }
  } else if (b < SU_W2P){
    int l = b - SU_EBW;
    if (tid < 128){
      int j = tid;
      long nb = (long)l*256*128 + 128*128;
      float acc = 0.f;
      for (int d=0; d<128; d++)
        acc += ldf(eb2, (long)l*128 + d, isbf) * ldf(nw1, nb + (long)d*128 + j, isbf);
      ebW[l*128+j] = acc;
    }
  } else if (b < SU_PPARM){
    int l = b - SU_W2P;
    int i = tid;
    long Woff = (long)l*128*128, poff = (long)l*129;
    if (i < 128){
      float acc = 0.f;
      for (int j=0;j<128;j++) acc += ldf(ew2, Woff + (long)i*128 + j, isbf) * ldf(pw1, poff + j, isbf);
      w2p[l*128+i] = acc;
      red[i] = ldf(eb2, (long)l*128 + i, isbf) * ldf(pw1, poff + i, isbf);
    }
    __syncthreads();
    for (int st=64; st>0; st>>=1){ if (i<st) red[i]+=red[i+st]; __syncthreads(); }
    if (i==0) c2p[l] = red[0];
  } else if (b == SU_PPARM){
    int l = tid;
    if (l < 4){
      pparm[l*4+0] = ldf(pw1, (long)l*129 + 128, isbf);
      pparm[l*4+1] = ldf(pb1, l, isbf);
      pparm[l*4+2] = ldf(pw2v, l, isbf);
      pparm[l*4+3] = ldf(pb2, l, isbf);
    }
  } else if (b < SU_CVTP){
    int n = (b - SU_PROJ)*2 + (tid>>7), d = tid & 127;
    if (n < NNODES){
      float acc = ldf(npb, d, isbf);
#pragma unroll
      for (int f=0; f<12; f++) acc += ldf(nf, (long)n*12+f, isbf) * ldf(npw, f*128+d, isbf);
      xb[swz(n, d)] = f2b(acc);   // swizzled residual layout
    }
  } else {
    int i = (b - SU_CVTP)*256 + tid;
    if (i < 2*NNODES) pf[i] = ldf(pos, i, isbf);
  }
}

// ---------- CSR build: histogram, 3-stage scan, scatter ----------
__global__ __launch_bounds__(256) void hist_kernel(const int* __restrict__ tgt, int* __restrict__ cnt, int E){
  int i = blockIdx.x*256 + threadIdx.x;
  if (i < E) atomicAdd(&cnt[tgt[i]], 1);
}

__global__ __launch_bounds__(256) void bsum_kernel(const int* __restrict__ cnt, int* __restrict__ bsum, int N){
  int i = blockIdx.x*256 + threadIdx.x;
  int v = (i < N) ? cnt[i] : 0;
#pragma unroll
  for (int off=32; off; off>>=1) v += __shfl_down(v, off);
  __shared__ int ws[4];
  if ((threadIdx.x & 63) == 0) ws[threadIdx.x>>6] = v;
  __syncthreads();
  if (threadIdx.x == 0) bsum[blockIdx.x] = ws[0]+ws[1]+ws[2]+ws[3];
}

__global__ __launch_bounds__(256) void bscan_kernel(int* __restrict__ bsum, int nb){
  __shared__ int lds[256];
  int i = threadIdx.x;
  int v = (i < nb) ? bsum[i] : 0;
  lds[i] = v; __syncthreads();
#pragma unroll
  for (int off=1; off<256; off<<=1){
    int t = (i>=off)? lds[i-off] : 0; __syncthreads();
    lds[i] += t; __syncthreads();
  }
  if (i < nb) bsum[i] = lds[i] - v;  // exclusive prefix
}

__global__ __launch_bounds__(256) void csr_kernel(
    const int* __restrict__ cnt, const int* __restrict__ bsum,
    int* __restrict__ rowptr, int* __restrict__ cursor, float* __restrict__ degf, int N)
{
  __shared__ int lds[256];
  int i = blockIdx.x*256 + threadIdx.x;
  int c = (i < N) ? cnt[i] : 0;
  lds[threadIdx.x] = c; __syncthreads();
#pragma unroll
  for (int off=1; off<256; off<<=1){
    int t = (threadIdx.x>=off)? lds[threadIdx.x-off] : 0; __syncthreads();
    lds[threadIdx.x] += t; __syncthreads();
  }
  int run = bsum[blockIdx.x] + lds[threadIdx.x] - c;  // exclusive
  if (i < N){
    rowptr[i] = run; cursor[i] = run; degf[i] = (float)c;
    if (i == N-1) rowptr[N] = run + c;
  }
}

__global__ __launch_bounds__(256) void scatter_kernel(
    const int* __restrict__ src, const int* __restrict__ tgt,
    int* __restrict__ cursor, int* __restrict__ permsrc, int E)
{
  int e = blockIdx.x*256 + threadIdx.x;
  if (e >= E) return;
  int t = tgt[e];
  int p = atomicAdd(&cursor[t], 1);
  permsrc[p] = src[e];
}

// ---------- single streaming matmul: Out = bf16(x@W [+ bias]) ----------
// X swizzled; W packed in LDS (32KB); Out row-major via per-wave 4KB LDS stage.
// LDS total 48KB -> 3 blocks/CU = 3 waves/SIMD.
__global__ __launch_bounds__(256, 3) void mm_single_kernel(
    const u16* __restrict__ X, const u16* __restrict__ W,
    const void* __restrict__ bias, long bias_off, int hasbias,
    u16* __restrict__ Out, const int* __restrict__ flagp)
{
  extern __shared__ u16 dls[];
  u16* wl = dls;                         // 16384 u16 = 32KB
  const int tid = threadIdx.x, wave = tid>>6, lane = tid&63;
  const int isbf = *flagp;
  const int lr = lane&15, lg = lane>>4;
  u16* sw = dls + 16384 + (wave<<11);    // per-wave 2048 u16 = 4KB
  for (int i=tid; i<2048; i+=256)
    *(bf16x8*)(wl + (long)i*8) = *(const bf16x8*)(W + (long)i*8);
  float biasv[8];
#pragma unroll
  for (int nt=0;nt<8;nt++) biasv[nt] = hasbias ? ldf(bias, bias_off + nt*16 + lr, isbf) : 0.f;
  int aoff[4];
#pragma unroll
  for (int kk=0;kk<4;kk++) aoff[kk] = ((2*kk + (lg>>1))*4 + (lr&3))*64 + (lr>>2)*16 + (lg&1)*8;
  __syncthreads();
  for (int tile = blockIdx.x*4 + wave; tile < NTILES; tile += SGRID*4){
    const u16* xt = X + (long)tile*2048;
    bf16x8 a[4];
#pragma unroll
    for (int kk=0;kk<4;kk++) a[kk] = *(const bf16x8*)(xt + aoff[kk]);
    floatx4 acc[8];
#pragma unroll
    for (int i=0;i<8;i++) acc[i]=(floatx4){0,0,0,0};
#pragma unroll
    for (int kk=0;kk<4;kk++){
#pragma unroll
      for (int nt=0;nt<8;nt++){
        bf16x8 b = *(const bf16x8*)(wl + ((kk*8+nt)*64 + lane)*8);
        acc[nt] = __builtin_amdgcn_mfma_f32_16x16x32_bf16(a[kk], b, acc[nt], 0, 0, 0);
      }
    }
    u16* ot = Out + (long)tile*2048;
#pragma unroll
    for (int r=0;r<4;r++){
#pragma unroll
      for (int nt=0;nt<8;nt++) sw[(lg*4+r)*128 + nt*16 + lr] = f2b(acc[nt][r] + biasv[nt]);
    }
#pragma unroll
    for (int j=0;j<4;j++){
      bf16x8 v = *(const bf16x8*)(sw + j*512 + lane*8);
      *(bf16x8*)(ot + j*512 + lane*8) = v;
    }
  }
}

// ---------- mega: h = silu(xb@NW1a + Hb@W12 + deg*ebW + nb1); res = xb + h@NW2 + nb2 ----------
// 512 threads, 8 waves. LDS: W1(32K) + W12(32K) + W2(32K) + 8x per-wave stage
// (2176 u16, row stride 136 = 272B, 16B-aligned) = 130KB -> 1 block/CU.
// h never touches HBM: C-frags -> LDS stage -> A-frags (per-wave, DS in-order).
// X and xb alias (same buffer, no __restrict__): each tile owned by one wave.
template<int LN>
__global__ __launch_bounds__(512, 2) void mega_kernel(
    const u16* X, const u16* __restrict__ H,
    const u16* __restrict__ W1, const u16* __restrict__ W12, const u16* __restrict__ W2,
    const void* __restrict__ nb1, long nb1_off,
    const void* __restrict__ nb2, long nb2_off,
    const float* __restrict__ degf, const float* __restrict__ ebW,
    u16* xb,
    const void* __restrict__ lng, const void* __restrict__ lnb, void* __restrict__ outp,
    const int* __restrict__ flagp)
{
  extern __shared__ u16 dls[];
  u16* w1s  = dls;
  u16* w12s = dls + 16384;
  u16* w2s  = dls + 32768;
  const int tid = threadIdx.x, wave = tid>>6, lane = tid&63;
  const int isbf = *flagp;
  const int lr = lane&15, lg = lane>>4;
  u16* stg = dls + 49152 + wave*2176;
  for (int i=tid; i<2048; i+=512){
    *(bf16x8*)(w1s  + (long)i*8) = *(const bf16x8*)(W1  + (long)i*8);
    *(bf16x8*)(w12s + (long)i*8) = *(const bf16x8*)(W12 + (long)i*8);
    *(bf16x8*)(w2s  + (long)i*8) = *(const bf16x8*)(W2  + (long)i*8);
  }
  float nb1v[8], nb2v[8], ebv[8];
#pragma unroll
  for (int nt=0;nt<8;nt++){
    int col = nt*16 + lr;
    nb1v[nt] = ldf(nb1, nb1_off + col, isbf);
    nb2v[nt] = ldf(nb2, nb2_off + col, isbf);
    ebv[nt]  = ebW[col];
  }
  float gv[8], bvv[8];
  if (LN){
#pragma unroll
    for (int nt=0;nt<8;nt++){ int col=nt*16+lr; gv[nt]=ldf(lng,col,isbf); bvv[nt]=ldf(lnb,col,isbf); }
  }
  int aoff[4];
#pragma unroll
  for (int kk=0;kk<4;kk++) aoff[kk] = ((2*kk + (lg>>1))*4 + (lr&3))*64 + (lr>>2)*16 + (lg&1)*8;
  __syncthreads();
  for (int tile = blockIdx.x*8 + wave; tile < NTILES; tile += MGRID*8){
    // ---- phase 1: hidden pre-activation ----
    const u16* xt = X + (long)tile*2048;
    const u16* hr = H + ((long)tile*16 + lr)*128;   // row-major Hb
    bf16x8 ax[4], ah[4];
#pragma unroll
    for (int kk=0;kk<4;kk++){
      ax[kk] = *(const bf16x8*)(xt + aoff[kk]);
      ah[kk] = *(const bf16x8*)(hr + kk*32 + lg*8);
    }
    floatx4 acc[8];
#pragma unroll
    for (int i=0;i<8;i++) acc[i]=(floatx4){0,0,0,0};
#pragma unroll
    for (int kk=0;kk<4;kk++){
#pragma unroll
      for (int nt=0;nt<8;nt++){
        bf16x8 b1 = *(const bf16x8*)(w1s + ((kk*8+nt)*64 + lane)*8);
        acc[nt] = __builtin_amdgcn_mfma_f32_16x16x32_bf16(ax[kk], b1, acc[nt], 0, 0, 0);
        bf16x8 b2 = *(const bf16x8*)(w12s + ((kk*8+nt)*64 + lane)*8);
        acc[nt] = __builtin_amdgcn_mfma_f32_16x16x32_bf16(ah[kk], b2, acc[nt], 0, 0, 0);
      }
    }
    float dv[4];
#pragma unroll
    for (int r=0;r<4;r++) dv[r] = degf[(long)tile*16 + lg*4 + r];
    // ---- stage h: C-frag -> row-major LDS (stride 136 = 272B, 16B aligned) ----
#pragma unroll
    for (int r=0;r<4;r++){
#pragma unroll
      for (int nt=0;nt<8;nt++)
        stg[(lg*4+r)*136 + nt*16 + lr] = f2b(siluf(acc[nt][r] + nb1v[nt] + dv[r]*ebv[nt]));
    }
    // ---- phase 2: h @ NW2 (A-frags from stage; per-wave DS in-order) ----
    bf16x8 ha[4];
#pragma unroll
    for (int kk=0;kk<4;kk++) ha[kk] = *(const bf16x8*)(stg + lr*136 + kk*32 + lg*8);
    floatx4 acc2[8];
#pragma unroll
    for (int i=0;i<8;i++) acc2[i]=(floatx4){0,0,0,0};
#pragma unroll
    for (int kk=0;kk<4;kk++){
#pragma unroll
      for (int nt=0;nt<8;nt++){
        bf16x8 b = *(const bf16x8*)(w2s + ((kk*8+nt)*64 + lane)*8);
        acc2[nt] = __builtin_amdgcn_mfma_f32_16x16x32_bf16(ha[kk], b, acc2[nt], 0, 0, 0);
      }
    }
    // ---- residual ----
    u16* xo = xb + (long)tile*2048;
#pragma unroll
    for (int r=0;r<4;r++){
#pragma unroll
      for (int nt=0;nt<8;nt++){
        int o = (nt*4+r)*64 + lane;           // full-line swizzled RMW
        float v = acc2[nt][r] + nb2v[nt] + b2f(xo[o]);
        acc2[nt][r] = v;
        if (!LN) xo[o] = f2b(v);
      }
    }
    if (LN){
      float s[4] = {0,0,0,0}, q[4] = {0,0,0,0};
#pragma unroll
      for (int r=0;r<4;r++){
#pragma unroll
        for (int nt=0;nt<8;nt++){ float v = acc2[nt][r]; s[r] += v; q[r] += v*v; }
      }
#pragma unroll
      for (int mask=1; mask<16; mask<<=1){
#pragma unroll
        for (int r=0;r<4;r++){ s[r] += __shfl_xor(s[r], mask); q[r] += __shfl_xor(q[r], mask); }
      }
      float mu4[4], inv4[4];
#pragma unroll
      for (int r=0;r<4;r++){
        float mu = s[r]*(1.f/128.f);
        float var = q[r]*(1.f/128.f) - mu*mu;
        mu4[r] = mu; inv4[r] = rsqrtf(var + 1e-5f);
      }
      if (isbf){
        // reuse stage (h frags already consumed) with 128-stride for contiguous rows
#pragma unroll
        for (int r=0;r<4;r++){
#pragma unroll
          for (int nt=0;nt<8;nt++)
            stg[(lg*4+r)*128 + nt*16 + lr] = f2b((acc2[nt][r]-mu4[r])*inv4[r]*gv[nt] + bvv[nt]);
        }
        u16* ot = (u16*)outp + (long)tile*2048;
#pragma unroll
        for (int j=0;j<4;j++){
          bf16x8 v = *(const bf16x8*)(stg + j*512 + lane*8);
          *(bf16x8*)(ot + j*512 + lane*8) = v;
        }
      } else {
#pragma unroll
        for (int r=0;r<4;r++){
          long row = (long)tile*16 + lg*4 + r;
#pragma unroll
          for (int nt=0;nt<8;nt++){
            int col = nt*16 + lr;
            ((float*)outp)[row*128+col] = (acc2[nt][r]-mu4[r])*inv4[r]*gv[nt] + bvv[nt];
          }
        }
      }
    }
  }
}

// ---------- CSR aggregation: persistent waves + packed edge-scalar phase ----------
// A/B/Hb row-major. One wave per node (grid-stride). Lane group cc=lane&3
// computes edge cc's scalars (1x sqrt/exp/rcp/rcp instead of 4x); dd broadcast
// back via readlane (SALU). dp accumulated per lane group, reduced at node end.
__global__ __launch_bounds__(256) void agg_kernel(
    const int* __restrict__ rowptr, const int* __restrict__ permsrc,
    const float* __restrict__ pf_in,
    const u16* __restrict__ A, const u16* __restrict__ B,
    const void* __restrict__ ew1, long w1c_off,
    const float* __restrict__ w2p, const float* __restrict__ c2pl,
    const float* __restrict__ pp,
    u16* __restrict__ Hb, float* __restrict__ pf_out, int N,
    const int* __restrict__ flagp)
{
  const int isbf = *flagp;
  int tid = threadIdx.x, lane = tid & 63;
  int wid = blockIdx.x*4 + (tid>>6);
  const int cc = lane & 3;
  // per-wave constants hoisted out of the node loop
  float c0 = ldf(ew1, w1c_off + 2*lane,     isbf);
  float c1 = ldf(ew1, w1c_off + 2*lane + 1, isbf);
  float2 wp = *(const float2*)(w2p + 2*lane);
  float c2 = c2pl[0];
  float p0 = pp[0], p1 = pp[1], p2 = pp[2], p3 = pp[3];
  for (int t = wid; t < N; t += AGWAVES){
    int tu = __builtin_amdgcn_readfirstlane(t);   // wave-uniform -> scalar loads
    int jb = rowptr[tu], je = rowptr[tu+1];
    float2 pt = *(const float2*)(pf_in + 2*(long)tu);
    unsigned bv = *(const unsigned*)(B + (long)tu*128 + 2*lane);
    float b0 = b2f((u16)bv), b1 = b2f((u16)(bv>>16));
    float h0a = 0.f, h1a = 0.f, dpx = 0.f, dpy = 0.f;
    for (int j0 = jb; j0 < je; j0 += 4){
      int m = je - j0; if (m > 4) m = 4;       // wave-uniform
      int s[4];
#pragma unroll
      for (int c=0;c<4;c++) s[c] = permsrc[j0 + (c<m ? c : 0)];
      // ---- packed scalar phase: lane group cc handles edge cc ----
      int scc = cc==0 ? s[0] : (cc==1 ? s[1] : (cc==2 ? s[2] : s[3]));
      float2 psc = *(const float2*)(pf_in + 2*(long)scc);
      float dxc = pt.x - psc.x, dyc = pt.y - psc.y;
      float ddc = __builtin_amdgcn_sqrtf(dxc*dxc + dyc*dyc);
      float dd_s[4];
#pragma unroll
      for (int c=0;c<4;c++) dd_s[c] = rdlane(ddc, c);   // SGPR broadcast
      // ---- column phase (required math, fully lane-utilized) ----
      unsigned av[4];
#pragma unroll
      for (int c=0;c<4;c++) if (c<m) av[c] = *(const unsigned*)(A + (long)s[c]*128 + 2*lane);
      float part[4];
#pragma unroll
      for (int c=0;c<4;c++){
        if (c<m){
          float h0 = siluf(b2f((u16)av[c])       + b0 + dd_s[c]*c0);
          float h1 = siluf(b2f((u16)(av[c]>>16)) + b1 + dd_s[c]*c1);
          h0a += h0; h1a += h1;
          part[c] = h0*wp.x + h1*wp.y;
        } else part[c] = 0.f;
      }
#pragma unroll
      for (int off=32; off; off>>=1){
#pragma unroll
        for (int c=0;c<4;c++) part[c] += __shfl_xor(part[c], off);
      }
      // ---- packed tail: pwv & pos contribution (1x trans each) ----
      float pc = cc==0 ? part[0] : (cc==1 ? part[1] : (cc==2 ? part[2] : part[3]));
      float sprec = pc + c2 + ddc*p0 + p1;
      float pwvc  = siluf(sprec)*p2 + p3;
      float invc  = __builtin_amdgcn_rcpf(ddc + 1e-6f);
      if (cc < m){ dpx += dxc*invc*pwvc; dpy += dyc*invc*pwvc; }
    }
    *(unsigned*)(Hb + (long)tu*128 + 2*lane) = (unsigned)f2b(h0a) | ((unsigned)f2b(h1a)<<16);
    // combine the 4 lane groups' dp partials
    dpx += __shfl_xor(dpx, 1); dpx += __shfl_xor(dpx, 2);
    dpy += __shfl_xor(dpy, 1); dpy += __shfl_xor(dpy, 2);
    if (lane == 0){
      float2 o; o.x = pt.x + dpx; o.y = pt.y + dpy;
      *(float2*)(pf_out + 2*(long)tu) = o;
    }
  }
}

extern "C" void kernel_launch(void* const* d_in, const int* in_sizes, int n_in,
                              void* d_out, int out_size, void* d_ws, size_t ws_size,
                              hipStream_t stream)
{
  const void* nf  = d_in[0];
  const void* pos = d_in[1];
  const void* npw = d_in[3];
  const void* npb = d_in[4];
  const void* ew1 = d_in[7];
  const void* eb1 = d_in[8];
  const void* ew2 = d_in[9];
  const void* eb2 = d_in[10];
  const void* nw1 = d_in[11];
  const void* nb1 = d_in[12];
  const void* nw2 = d_in[13];
  const void* nb2 = d_in[14];
  const void* pw1 = d_in[15];
  const void* pb1 = d_in[16];
  const void* pw2 = d_in[17];
  const void* pb2 = d_in[18];
  const void* lng = d_in[19];
  const void* lnb = d_in[20];
  const int* eidx = (const int*)d_in[21];
  const int N = NNODES, E = NEDGES;
  const int* srcp = eidx;
  const int* tgtp = eidx + E;

  char* w = (char*)d_ws;
  size_t off = 0;
  auto alloc = [&](size_t bytes)->char* { char* p = w + off; off += (bytes + 255)/256*256; return p; };
  u16*   xb    = (u16*)  alloc((size_t)N*128*2);
  u16*   Ab    = (u16*)  alloc((size_t)N*128*2);
  u16*   Bb    = (u16*)  alloc((size_t)N*128*2);
  u16*   Hb    = (u16*)  alloc((size_t)N*128*2);
  float* pf0   = (float*)alloc((size_t)N*2*4);
  float* pf1   = (float*)alloc((size_t)N*2*4);
  int*   cnt   = (int*)  alloc((size_t)N*4);
  int*   rowptr= (int*)  alloc((size_t)(N+1)*4);
  int*   cursor= (int*)  alloc((size_t)N*4);
  float* degf  = (float*)alloc((size_t)N*4);
  int*   perm  = (int*)  alloc((size_t)E*4);
  int*   bsum  = (int*)  alloc(256*4);
  u16*   pk    = (u16*)  alloc((size_t)28*16384*2);
  float* ebW   = (float*)alloc(4*128*4);
  float* w2p   = (float*)alloc(4*128*4);
  float* c2p   = (float*)alloc(4*4);
  float* pparm = (float*)alloc(16*4);
  int*   flag  = (int*)  alloc(4);

  const int NB = (N + 255)/256;  // 196 <= 256
  detect_kernel<<<1, 64, 0, stream>>>(lng, flag);
  hipMemsetAsync(cnt, 0, (size_t)N*4, stream);
  hist_kernel<<<(E+255)/256, 256, 0, stream>>>(tgtp, cnt, E);
  bsum_kernel<<<NB, 256, 0, stream>>>(cnt, bsum, N);
  bscan_kernel<<<1, 256, 0, stream>>>(bsum, NB);
  csr_kernel<<<NB, 256, 0, stream>>>(cnt, bsum, rowptr, cursor, degf, N);
  scatter_kernel<<<(E+255)/256, 256, 0, stream>>>(srcp, tgtp, cursor, perm, E);
  setup_kernel<<<SU_END, 256, 0, stream>>>(
      ew1, ew2, nw1, nw2, pk,
      eb2, pw1, pb1, pw2, pb2,
      w2p, c2p, pparm, ebW,
      nf, npw, npb, xb,
      pos, pf0, flag);

  // layer 0 A/B from projected x (split kernels: 48KB LDS -> 3 blocks/CU)
  mm_single_kernel<<<SGRID, 256, 49152, stream>>>(xb, pk + 0*16384, eb1, 0, 1, Ab, flag);
  mm_single_kernel<<<SGRID, 256, 49152, stream>>>(xb, pk + 1*16384, nullptr, 0, 0, Bb, flag);
  for (int l = 0; l < 4; l++){
    const u16* NW1a = pk + (l*6+3)*16384;
    const u16* NW2p = pk + (l*6+5)*16384;
    const u16* W12p = pk + (24+l)*16384;
    float* pin  = (l & 1) ? pf1 : pf0;
    float* pout = (l & 1) ? pf0 : pf1;

    agg_kernel<<<AGGRID, 256, 0, stream>>>(
        rowptr, perm, pin, Ab, Bb,
        ew1, (long)l*257*128 + 256*128,
        w2p + l*128, c2p + l, pparm + l*4,
        Hb, pout, N, flag);
    if (l < 3){
      mega_kernel<0><<<MGRID, 512, 133120, stream>>>(
          xb, Hb, NW1a, W12p, NW2p, nb1, (long)l*128, nb2, (long)l*128,
          degf, ebW + l*128, xb, nullptr, nullptr, nullptr, flag);
      mm_single_kernel<<<SGRID, 256, 49152, stream>>>(
          xb, pk + ((l+1)*6+0)*16384, eb1, (long)(l+1)*128, 1, Ab, flag);
      mm_single_kernel<<<SGRID, 256, 49152, stream>>>(
          xb, pk + ((l+1)*6+1)*16384, nullptr, 0, 0, Bb, flag);
    } else {
      mega_kernel<1><<<MGRID, 512, 133120, stream>>>(
          xb, Hb, NW1a, W12p, NW2p, nb1, (long)l*128, nb2, (long)l*128,
          degf, ebW + l*128, xb, lng, lnb, d_out, flag);
    }
  }
}